// Round 9
// baseline (248.611 us; speedup 1.0000x reference)
//
#include <hip/hip_runtime.h>
#include <math.h>

#define D_MODEL 256
#define NHEAD   8
#define NLVL    4
#define NPTS    4
#define DHEAD   32
#define DFFN    1024
#define NQ      900
#define BSZ     4
#define NROW    (NQ * BSZ)      // 3600
#define NROWP   3648            // padded to 57*64
#define S_TOT   11253
#define VROWS   (S_TOT * BSZ)   // 45012
#define SASCALE 0.17677669529663687f

typedef __attribute__((ext_vector_type(8))) short short8;
typedef __attribute__((ext_vector_type(4))) float f32x4;
typedef unsigned short ushort_t;

static __device__ __forceinline__ unsigned f2bf1(float f) {
    unsigned u = __float_as_uint(f);
    return (u + 0x7FFFu + ((u >> 16) & 1u)) >> 16;
}
static __device__ __forceinline__ unsigned pack2bf(float x, float y) {
    return f2bf1(x) | (f2bf1(y) << 16);
}
static __device__ __forceinline__ float bf2f(ushort_t u) {
    return __uint_as_float(((unsigned)u) << 16);
}

#if __has_builtin(__builtin_amdgcn_global_load_lds)
#define HAS_GLL 1
#endif

static __device__ __forceinline__ void stage_w16(const ushort_t* g, ushort_t* ldsbase, int lane)
{
#ifdef HAS_GLL
    __builtin_amdgcn_global_load_lds(
        (const __attribute__((address_space(1))) unsigned int*)g,
        (__attribute__((address_space(3))) unsigned int*)ldsbase, 16, 0, 0);
#else
    *(uint4*)(ldsbase + lane * 8) = *(const uint4*)g;
#endif
}

// bf16 weight buffer element offsets
#define WB_IN   0         // 768*256
#define WB_VP   196608    // 256*256
#define WB_OUTP 262144    // 256*256
#define WB_OFF  327680    // 256*256
#define WB_AW   393216    // 128*256
#define WB_OP   425984    // 256*256
#define WB_L1   491520    // 1024*256
#define WB_L2   753664    // 256*1024
#define WB_TOT  1015808

// ---------------------------------------------------------------------------
// cvt_weights (R18): weights (pre-swizzled) + qkv A-input pre-conversion:
//   tgt16 = bf16(tgt), tq16 = bf16(tgt+qpos) — pre-swizzled, padded to 3648.
// Swizzle: k' = (k & ~63) | ((k&63) ^ ((row&7)<<3)).
// Grid: 496 weights + 456 tgt16 + 456 tq16 = 1408 blocks.
// ---------------------------------------------------------------------------
__global__ __launch_bounds__(256) void cvt_weights(
    const float* __restrict__ w_in, const float* __restrict__ w_vp,
    const float* __restrict__ w_outp, const float* __restrict__ w_off,
    const float* __restrict__ w_aw, const float* __restrict__ w_op,
    const float* __restrict__ w_l1, const float* __restrict__ w_l2,
    ushort_t* __restrict__ dst,
    const float* __restrict__ tgt, const float* __restrict__ qpos,
    ushort_t* __restrict__ tgt16, ushort_t* __restrict__ tq16)
{
    int b = blockIdx.x;
    if (b < 496) {
        const float* src;
        int dstoff;
        int kbits = 8;
        if (b < 96)       { src = w_in;   dstoff = WB_IN;   }
        else if (b < 128) { src = w_vp;   b -= 96;  dstoff = WB_VP;   }
        else if (b < 160) { src = w_outp; b -= 128; dstoff = WB_OUTP; }
        else if (b < 192) { src = w_off;  b -= 160; dstoff = WB_OFF;  }
        else if (b < 208) { src = w_aw;   b -= 192; dstoff = WB_AW;   }
        else if (b < 240) { src = w_op;   b -= 208; dstoff = WB_OP;   }
        else if (b < 368) { src = w_l1;   b -= 240; dstoff = WB_L1;   }
        else              { src = w_l2;   b -= 368; dstoff = WB_L2;   kbits = 10; }
        int i = (b * 256 + threadIdx.x) * 8;
        float4 f0 = *(const float4*)(src + i);
        float4 f1 = *(const float4*)(src + i + 4);
        uint4 u;
        u.x = pack2bf(f0.x, f0.y); u.y = pack2bf(f0.z, f0.w);
        u.z = pack2bf(f1.x, f1.y); u.w = pack2bf(f1.z, f1.w);
        int K = 1 << kbits;
        int n = i >> kbits;
        int k = i & (K - 1);
        int kswz = (k & ~63) | ((k & 63) ^ ((n & 7) << 3));
        *(uint4*)(dst + dstoff + (size_t)n * K + kswz) = u;
    } else {
        int bb = b - 496;
        ushort_t* dbuf = tgt16;
        bool addq = false;
        if (bb >= 456) { bb -= 456; dbuf = tq16; addq = true; }
        int i = bb * 2048 + threadIdx.x * 8;     // < 933888 (exact, no tail)
        int row = i >> 8, k = i & 255;
        uint4 u = make_uint4(0u, 0u, 0u, 0u);
        if (row < NROW) {
            const float* sp = tgt + (size_t)row * 256 + k;
            float4 f0 = *(const float4*)(sp + 0);
            float4 f1 = *(const float4*)(sp + 4);
            if (addq) {
                const float* qp = qpos + (size_t)row * 256 + k;
                float4 q0 = *(const float4*)(qp + 0);
                float4 q1 = *(const float4*)(qp + 4);
                f0.x += q0.x; f0.y += q0.y; f0.z += q0.z; f0.w += q0.w;
                f1.x += q1.x; f1.y += q1.y; f1.z += q1.z; f1.w += q1.w;
            }
            u.x = pack2bf(f0.x, f0.y); u.y = pack2bf(f0.z, f0.w);
            u.z = pack2bf(f1.x, f1.y); u.w = pack2bf(f1.z, f1.w);
        }
        int kswz = (k & ~63) | ((k & 63) ^ ((row & 7) << 3));
        *(uint4*)(dbuf + (size_t)row * 256 + kswz) = u;
    }
}

// ---------------------------------------------------------------------------
// proj_fused (R19): both paths DOUBLE-BUFFERED.
// qkv: A (tq16/tgt16) + W all via gll — staging of phase k+1 is pure
// fire-and-forget into buf^1 while MFMAs consume buf.
// vproj: Ws dbuf (2x32KB gll) + As dbuf (2x8KB fp32-convert path, write-side
// swizzle). gll W issues before the MFMAs; the A convert runs after them so
// its load latency hides under the MFMA burst. LDS 80KB -> 2 blocks/CU.
// ---------------------------------------------------------------------------
__global__ __launch_bounds__(256) void proj_fused(
    const ushort_t* __restrict__ tq16, const ushort_t* __restrict__ tgt16,
    const ushort_t* __restrict__ in_wb, const float* __restrict__ in_b,
    const float* __restrict__ mem, const ushort_t* __restrict__ vp_wb,
    const float* __restrict__ vp_b,
    ushort_t* __restrict__ qkv16, ushort_t* __restrict__ value16)
{
    __shared__ ushort_t As[2][64 * 64];   // 16 KB
    __shared__ ushort_t Ws[2][256 * 64];  // 64 KB (qkv uses rows 0..63)

    const int t    = threadIdx.x;
    const int bid  = blockIdx.x;
    const int wv   = t >> 6;
    const int ln   = t & 63;
    const int L    = ln & 15;
    const int quad = ln >> 4;
    const int swz  = (L & 7) << 3;
    const int lrow = ln >> 3;
    const int lchk = (ln & 7) << 3;

    if (bid < 684) {
        const int m0 = (bid % 57) * 64;
        const int n0 = (bid / 57) * 64;
        const float oscale = (n0 < 256) ? SASCALE : 1.f;
        const ushort_t* Ab = (n0 < 512) ? tq16 : tgt16;

        auto stageQ = [&](int k0, int buf) {
#pragma unroll
            for (int j = 0; j < 2; ++j) {
                int r0 = (wv * 2 + j) * 8;
                stage_w16(Ab + (size_t)(m0 + r0 + lrow) * 256 + k0 + lchk, &As[buf][r0 * 64], ln);
                stage_w16(in_wb + (size_t)(n0 + r0 + lrow) * 256 + k0 + lchk, &Ws[buf][r0 * 64], ln);
            }
        };

        f32x4 acc[4] = {{0.f,0.f,0.f,0.f},{0.f,0.f,0.f,0.f},
                        {0.f,0.f,0.f,0.f},{0.f,0.f,0.f,0.f}};

        stageQ(0, 0);
        __syncthreads();
        int cur = 0;
        for (int k = 0; k < 4; ++k) {
            if (k < 3) stageQ((k + 1) * 64, cur ^ 1);
#pragma unroll
            for (int kh = 0; kh < 2; ++kh) {
                int ko = (kh * 32 + quad * 8) ^ swz;
                short8 af = *(const short8*)&As[cur][(wv * 16 + L) * 64 + ko];
#pragma unroll
                for (int cb = 0; cb < 4; ++cb) {
                    short8 bf = *(const short8*)&Ws[cur][(cb * 16 + L) * 64 + ko];
                    acc[cb] = __builtin_amdgcn_mfma_f32_16x16x32_bf16(af, bf, acc[cb], 0, 0, 0);
                }
            }
            __syncthreads();
            cur ^= 1;
        }
#pragma unroll
        for (int cb = 0; cb < 4; ++cb) {
            int col = n0 + cb * 16 + L;
            float bv = in_b[col];
#pragma unroll
            for (int i = 0; i < 4; ++i) {
                int m = m0 + wv * 16 + quad * 4 + i;
                if (m < NROW)
                    qkv16[(size_t)m * 768 + col] = (ushort_t)f2bf1((acc[cb][i] + bv) * oscale);
            }
        }
    } else {
        const int vb = bid - 684;        // 0..703
        const int m0 = vb * 64;
        const int trow = t >> 2;
        const int tk   = (t & 3) << 4;
        const int wsz  = (trow & 7) << 3;    // write-side swizzle

        const int  mrow = m0 + trow;
        const bool mv   = (mrow < VROWS);
        const float* arow = mem + (size_t)mrow * 256 + tk;

        auto stageWv = [&](int k0, int buf) {
#pragma unroll
            for (int j = 0; j < 8; ++j) {
                int r0 = (wv * 8 + j) * 8;
                stage_w16(vp_wb + (size_t)(r0 + lrow) * 256 + k0 + lchk, &Ws[buf][r0 * 64], ln);
            }
        };
        auto stageAv = [&](int k0, int buf) {
            uint4 u0, u1;
            if (mv) {
                const float* ap = arow + k0;
                float4 a0 = *(const float4*)(ap + 0);
                float4 a1 = *(const float4*)(ap + 4);
                float4 a2 = *(const float4*)(ap + 8);
                float4 a3 = *(const float4*)(ap + 12);
                u0.x = pack2bf(a0.x, a0.y); u0.y = pack2bf(a0.z, a0.w);
                u0.z = pack2bf(a1.x, a1.y); u0.w = pack2bf(a1.z, a1.w);
                u1.x = pack2bf(a2.x, a2.y); u1.y = pack2bf(a2.z, a2.w);
                u1.z = pack2bf(a3.x, a3.y); u1.w = pack2bf(a3.z, a3.w);
            } else {
                u0 = make_uint4(0u, 0u, 0u, 0u); u1 = u0;
            }
            *(uint4*)&As[buf][trow * 64 + (tk ^ wsz)]       = u0;
            *(uint4*)&As[buf][trow * 64 + ((tk + 8) ^ wsz)] = u1;
        };

        f32x4 acc[16];
#pragma unroll
        for (int i = 0; i < 16; ++i) acc[i] = (f32x4){0.f, 0.f, 0.f, 0.f};

        stageWv(0, 0);
        stageAv(0, 0);
        __syncthreads();
        int cur = 0;
        for (int k = 0; k < 4; ++k) {
            if (k < 3) stageWv((k + 1) * 64, cur ^ 1);   // async gll, no wave stall
#pragma unroll
            for (int kh = 0; kh < 2; ++kh) {
                int ko = (kh * 32 + quad * 8) ^ swz;
                short8 af = *(const short8*)&As[cur][(wv * 16 + L) * 64 + ko];
#pragma unroll
                for (int cb = 0; cb < 16; ++cb) {
                    short8 bf = *(const short8*)&Ws[cur][(cb * 16 + L) * 64 + ko];
                    acc[cb] = __builtin_amdgcn_mfma_f32_16x16x32_bf16(af, bf, acc[cb], 0, 0, 0);
                }
            }
            if (k < 3) stageAv((k + 1) * 64, cur ^ 1);   // loads hide under MFMAs
            __syncthreads();
            cur ^= 1;
        }

        // epilogue: bias + bf16, repack through LDS (two 128-col passes)
        ushort_t* Cs = Ws[0];   // 64 rows x 136 stride = 17408 B <= 32 KB
#pragma unroll
        for (int half = 0; half < 2; ++half) {
            if (half) __syncthreads();
#pragma unroll
            for (int cb = 0; cb < 8; ++cb) {
                int col = cb * 16 + L;
                float bv = vp_b[half * 128 + col];
#pragma unroll
                for (int i = 0; i < 4; ++i) {
                    int r = wv * 16 + quad * 4 + i;
                    Cs[r * 136 + col] = (ushort_t)f2bf1(acc[half * 8 + cb][i] + bv);
                }
            }
            __syncthreads();
            {
                int r  = t >> 2;
                int ch = (t & 3) * 32;
                int m  = m0 + r;
                if (m < VROWS) {
                    const ushort_t* src = &Cs[r * 136 + ch];
                    uint4* dst = (uint4*)(value16 + (size_t)m * 256 + half * 128 + ch);
#pragma unroll
                    for (int j = 0; j < 4; ++j)
                        dst[j] = *(const uint4*)(src + j * 8);
                }
            }
        }
    }
}

// ---------------------------------------------------------------------------
// MFMA flash self-attention (unchanged).
// ---------------------------------------------------------------------------
__global__ __launch_bounds__(256) void sa_flash16(
    const ushort_t* __restrict__ qkv, ushort_t* __restrict__ attn_out)
{
    __shared__ ushort_t Ks[2 * 2080];
    __shared__ ushort_t Vt[2 * 2304];
    __shared__ ushort_t Ps[4 * 1152];

    const int t    = threadIdx.x;
    const int q0   = blockIdx.x * 64;
    const int b    = blockIdx.y & 3;
    const int h    = blockIdx.y >> 2;
    const int wv   = t >> 6;
    const int ln   = t & 63;
    const int L    = ln & 15;
    const int quad = ln >> 4;

    union { uint4 u; short8 s; } qu;
    qu.u = make_uint4(0u, 0u, 0u, 0u);
    {
        int q = q0 + wv * 16 + L;
        if (q < NQ)
            qu.u = *(const uint4*)(qkv + ((size_t)q * 4 + b) * 768 + h * 32 + quad * 8);
    }
    const short8 qf = qu.s;

    float mrun = -1e30f, lrun = 0.f;
    f32x4 oacc[2] = {{0.f,0.f,0.f,0.f},{0.f,0.f,0.f,0.f}};

    const int skey = t >> 2;
    const int sdg  = t & 3;

    uint4 ku, vu;
    auto kv_load = [&](int k0) {
        int kg = k0 + skey;
        ku = make_uint4(0u, 0u, 0u, 0u);
        vu = make_uint4(0u, 0u, 0u, 0u);
        if (kg < NQ) {
            const ushort_t* base = qkv + ((size_t)kg * 4 + b) * 768 + 256 + h * 32 + sdg * 8;
            ku = *(const uint4*)base;
            vu = *(const uint4*)(base + 256);
        }
    };

    kv_load(0);
    int it = 0;
    for (int k0 = 0; k0 < NQ; k0 += 64, it ^= 1) {
        *(uint4*)&Ks[it * 2080 + sdg * 520 + skey * 8] = ku;
        {
            ushort_t* vp = &Vt[it * 2304 + sdg * 8 * 72 + skey];
            vp[0 * 72] = (ushort_t)(vu.x & 0xffffu);
            vp[1 * 72] = (ushort_t)(vu.x >> 16);
            vp[2 * 72] = (ushort_t)(vu.y & 0xffffu);
            vp[3 * 72] = (ushort_t)(vu.y >> 16);
            vp[4 * 72] = (ushort_t)(vu.z & 0xffffu);
            vp[5 * 72] = (ushort_t)(vu.z >> 16);
            vp[6 * 72] = (ushort_t)(vu.w & 0xffffu);
            vp[7 * 72] = (ushort_t)(vu.w >> 16);
        }
        __syncthreads();
        if (k0 + 64 < NQ) kv_load(k0 + 64);

        f32x4 sacc[4] = {{0.f,0.f,0.f,0.f},{0.f,0.f,0.f,0.f},
                         {0.f,0.f,0.f,0.f},{0.f,0.f,0.f,0.f}};
#pragma unroll
        for (int cb = 0; cb < 4; ++cb) {
            short8 kf = *(const short8*)&Ks[it * 2080 + quad * 520 + (cb * 16 + L) * 8];
            sacc[cb] = __builtin_amdgcn_mfma_f32_16x16x32_bf16(kf, qf, sacc[cb], 0, 0, 0);
        }
        if (k0 + 64 > NQ) {
#pragma unroll
            for (int cb = 0; cb < 4; ++cb)
#pragma unroll
                for (int i = 0; i < 4; ++i)
                    if (k0 + cb * 16 + quad * 4 + i >= NQ) sacc[cb][i] = -1e30f;
        }

        float ml = -1e30f;
#pragma unroll
        for (int cb = 0; cb < 4; ++cb)
#pragma unroll
            for (int i = 0; i < 4; ++i) ml = fmaxf(ml, sacc[cb][i]);
        ml = fmaxf(ml, __shfl_xor(ml, 16, 64));
        ml = fmaxf(ml, __shfl_xor(ml, 32, 64));
        float mnew  = fmaxf(mrun, ml);
        float alpha = __expf(mrun - mnew);
        float p[16];
        float rs = 0.f;
#pragma unroll
        for (int cb = 0; cb < 4; ++cb)
#pragma unroll
            for (int i = 0; i < 4; ++i) {
                float e = __expf(sacc[cb][i] - mnew);
                p[cb * 4 + i] = e;
                rs += e;
            }
        rs += __shfl_xor(rs, 16, 64);
        rs += __shfl_xor(rs, 32, 64);
        lrun = lrun * alpha + rs;
        mrun = mnew;

        {
            ushort_t* pw = &Ps[wv * 1152 + L * 72];
#pragma unroll
            for (int cb = 0; cb < 4; ++cb) {
                uint2 u;
                u.x = pack2bf(p[cb * 4 + 0], p[cb * 4 + 1]);
                u.y = pack2bf(p[cb * 4 + 2], p[cb * 4 + 3]);
                *(uint2*)&pw[cb * 16 + quad * 4] = u;
            }
        }
#pragma unroll
        for (int i = 0; i < 4; ++i) {
            float ai = __shfl(alpha, quad * 4 + i, 64);
            oacc[0][i] *= ai;
            oacc[1][i] *= ai;
        }
        __syncthreads();

#pragma unroll
        for (int ks = 0; ks < 2; ++ks) {
            short8 pf = *(const short8*)&Ps[wv * 1152 + L * 72 + ks * 32 + quad * 8];
#pragma unroll
            for (int db = 0; db < 2; ++db) {
                short8 vf = *(const short8*)&Vt[it * 2304 + (db * 16 + L) * 72 + ks * 32 + quad * 8];
                oacc[db] = __builtin_amdgcn_mfma_f32_16x16x32_bf16(pf, vf, oacc[db], 0, 0, 0);
            }
        }
    }

#pragma unroll
    for (int i = 0; i < 4; ++i) {
        float lq = __shfl(lrun, quad * 4 + i, 64);
        float li = 1.f / lq;
        int q = q0 + wv * 16 + quad * 4 + i;
        if (q < NQ) {
            ushort_t* op = attn_out + ((size_t)q * 4 + b) * 256 + h * 32 + L;
            op[0]  = (ushort_t)f2bf1(oacc[0][i] * li);
            op[16] = (ushort_t)f2bf1(oacc[1][i] * li);
        }
    }
}

// ---------------------------------------------------------------------------
// fused_ca (unchanged from R8): oproj+LN2 + off GEMM + aw GEMM + softmax.
// ---------------------------------------------------------------------------
__global__ __launch_bounds__(512, 1) void fused_ca(
    const ushort_t* __restrict__ att16,
    const float* __restrict__ tgt, const float* __restrict__ qpos,
    const ushort_t* __restrict__ outp_wb, const float* __restrict__ outp_b,
    const float* __restrict__ ln2g, const float* __restrict__ ln2b,
    const ushort_t* __restrict__ off_wb, const float* __restrict__ off_b,
    const ushort_t* __restrict__ aw_wb, const float* __restrict__ aw_b,
    const float* __restrict__ refp,
    float* __restrict__ tgt_a, float* __restrict__ px_g,
    float* __restrict__ py_g, float* __restrict__ aw_g)
{
    __shared__ ushort_t Ws[2][256 * 64];   // 64 KB
    __shared__ ushort_t att_s[16 * 264];
    __shared__ ushort_t xca_s[16 * 264];
    __shared__ float    aws_s[16 * 128];
    __shared__ float    sS[8][16], s2S[8][16];

    const int t    = threadIdx.x;
    const int m0   = blockIdx.x * 16;
    const int wv   = t >> 6;       // 0..7
    const int ln   = t & 63;
    const int L    = ln & 15;
    const int quad = ln >> 4;
    const int swz  = (L & 7) << 3;
    const int lrow = ln >> 3;
    const int lchk = (ln & 7) << 3;
    const int rloc = quad * 4;

    auto stage4 = [&](const ushort_t* base, int buf) {   // 256 rows, stride 256
#pragma unroll
        for (int j = 0; j < 4; ++j) {
            int r0 = (wv * 4 + j) * 8;
            stage_w16(base + (size_t)(r0 + lrow) * 256 + lchk, &Ws[buf][r0 * 64], ln);
        }
    };
    auto stage2 = [&](const ushort_t* base, int buf) {   // 128 rows, stride 256
#pragma unroll
        for (int j = 0; j < 2; ++j) {
            int r0 = (wv * 2 + j) * 8;
            stage_w16(base + (size_t)(r0 + lrow) * 256 + lchk, &Ws[buf][r0 * 64], ln);
        }
    };
    auto mfma2 = [&](const ushort_t* A, int koff, int buf, f32x4* acc) {
#pragma unroll
        for (int kh = 0; kh < 2; ++kh) {
            int ko = (kh * 32 + quad * 8) ^ swz;
            short8 af = *(const short8*)&A[L * 264 + koff + kh * 32 + quad * 8];
#pragma unroll
            for (int cb = 0; cb < 2; ++cb) {
                short8 bf = *(const short8*)&Ws[buf][(wv * 32 + cb * 16 + L) * 64 + ko];
                acc[cb] = __builtin_amdgcn_mfma_f32_16x16x32_bf16(af, bf, acc[cb], 0, 0, 0);
            }
        }
    };

    // load att16 tile (16x256 bf16 = 8 KB, one uint4 per thread)
    {
        int r = t >> 5, s = (t & 31) * 8;
        *(uint4*)&att_s[r * 264 + s] = *(const uint4*)(att16 + (size_t)(m0 + r) * 256 + s);
    }
    stage4(outp_wb, 0);
    __syncthreads();
    int cur = 0;

    // ---- oproj + LN2 ----
    {
        f32x4 acc[2] = {{0.f,0.f,0.f,0.f},{0.f,0.f,0.f,0.f}};
        for (int k = 0; k < 4; ++k) {
            if (k < 3) stage4(outp_wb + (k + 1) * 64, cur ^ 1);
            else       stage4(off_wb, cur ^ 1);
            mfma2(att_s, k * 64, cur, acc);
            __syncthreads();
            cur ^= 1;
        }
        float s[4] = {0.f,0.f,0.f,0.f}, s2v[4] = {0.f,0.f,0.f,0.f};
#pragma unroll
        for (int cb = 0; cb < 2; ++cb) {
            int col = wv * 32 + cb * 16 + L;
            float bv = outp_b[col];
#pragma unroll
            for (int i = 0; i < 4; ++i) {
                float xv = acc[cb][i] + bv + tgt[(size_t)(m0 + rloc + i) * 256 + col];
                acc[cb][i] = xv;
                s[i] += xv; s2v[i] += xv * xv;
            }
        }
#pragma unroll
        for (int off = 1; off < 16; off <<= 1)
#pragma unroll
            for (int i = 0; i < 4; ++i) {
                s[i]   += __shfl_xor(s[i],   off, 64);
                s2v[i] += __shfl_xor(s2v[i], off, 64);
            }
        if (L == 0)
#pragma unroll
            for (int i = 0; i < 4; ++i) { sS[wv][rloc + i] = s[i]; s2S[wv][rloc + i] = s2v[i]; }
        __syncthreads();
        float mean[4], rstd[4];
#pragma unroll
        for (int i = 0; i < 4; ++i) {
            float St = 0.f, S2t = 0.f;
#pragma unroll
            for (int w = 0; w < 8; ++w) { St += sS[w][rloc + i]; S2t += s2S[w][rloc + i]; }
            mean[i] = St * (1.f / 256.f);
            float var = S2t * (1.f / 256.f) - mean[i] * mean[i];
            rstd[i] = rsqrtf(var + 1e-5f);
        }
#pragma unroll
        for (int cb = 0; cb < 2; ++cb) {
            int col = wv * 32 + cb * 16 + L;
            float gv = ln2g[col], bt = ln2b[col];
#pragma unroll
            for (int i = 0; i < 4; ++i) {
                float y = (acc[cb][i] - mean[i]) * rstd[i] * gv + bt;
                tgt_a[(size_t)(m0 + rloc + i) * 256 + col] = y;
                xca_s[(rloc + i) * 264 + col] =
                    (ushort_t)f2bf1(y + qpos[(size_t)(m0 + rloc + i) * 256 + col]);
            }
        }
        __syncthreads();
    }

    // ---- sampling-offset GEMM -> px/py ----
    {
        f32x4 acc[2] = {{0.f,0.f,0.f,0.f},{0.f,0.f,0.f,0.f}};
        for (int k = 0; k < 4; ++k) {
            if (k < 3) stage4(off_wb + (k + 1) * 64, cur ^ 1);
            else       stage2(aw_wb, cur ^ 1);
            mfma2(xca_s, k * 64, cur, acc);
            __syncthreads();
            cur ^= 1;
        }
        const float dims[4] = {92.f, 46.f, 23.f, 12.f};
#pragma unroll
        for (int cb = 0; cb < 2; ++cb) {
            int col = wv * 32 + cb * 16 + L;
            float bv = off_b[col];
            int hh = col >> 5, lp = (col & 31) >> 1, isY = col & 1;
            int l = lp >> 2;
            float dim = dims[l];
            float* dst = isY ? py_g : px_g;
#pragma unroll
            for (int i = 0; i < 4; ++i) {
                int row = m0 + rloc + i;
                float ref = refp[((size_t)row * 4 + l) * 2 + isY];
                dst[(size_t)row * 128 + hh * 16 + lp] = ref * dim + (acc[cb][i] + bv) - 0.5f;
            }
        }
    }

    // ---- attention-weight GEMM (N=128) ----
    {
        f32x4 acc = {0.f, 0.f, 0.f, 0.f};
        for (int k = 0; k < 4; ++k) {
            if (k < 3) stage2(aw_wb + (k + 1) * 64, cur ^ 1);
#pragma unroll
            for (int kh = 0; kh < 2; ++kh) {
                int ko = (kh * 32 + quad * 8) ^ swz;
                short8 af = *(const short8*)&xca_s[L * 264 + k * 64 + kh * 32 + quad * 8];
                short8 bf = *(const short8*)&Ws[cur][(wv * 16 + L) * 64 + ko];
                acc = __builtin_amdgcn_mfma_f32_16x16x32_bf16(af, bf, acc, 0, 0, 0);
            }
            __syncthreads();
            cur ^= 1;
        }
        {
            int col = wv * 16 + L;
            float bv = aw_b[col];
#pragma unroll
            for (int i = 0; i < 4; ++i)
                aws_s[(rloc + i) * 128 + col] = acc[i] + bv;
        }
        __syncthreads();
    }

    // ---- softmax -> aw_g ----
    if (t < 128) {
        int r = t >> 3, hh = t & 7;
        float v[16];
        float m = -1e30f;
#pragma unroll
        for (int j = 0; j < 16; ++j) { v[j] = aws_s[r * 128 + hh * 16 + j]; m = fmaxf(m, v[j]); }
        float ssum = 0.f;
#pragma unroll
        for (int j = 0; j < 16; ++j) { v[j] = __expf(v[j] - m); ssum += v[j]; }
        float inv = 1.f / ssum;
#pragma unroll
        for (int j = 0; j < 16; ++j)
            aw_g[(size_t)(m0 + r) * 128 + hh * 16 + j] = v[j] * inv;
    }
}

// ---------------------------------------------------------------------------
// msdeform4: deformable sampling, d-vectorized 4x (unchanged).
// ---------------------------------------------------------------------------
__global__ __launch_bounds__(256) void msdeform4(
    const float* __restrict__ px_g, const float* __restrict__ py_g,
    const float* __restrict__ aw_g, const ushort_t* __restrict__ value16,
    ushort_t* __restrict__ out)
{
    const int t   = threadIdx.x;
    const int row = blockIdx.x * 4 + (t >> 6);
    const int ln  = t & 63;
    const int h   = ln >> 3;
    const int d   = (ln & 7) * 4;
    const int b   = row & 3;

    const int HsI[4] = {92, 46, 23, 12};
    const int S0_[4] = {0, 8464, 10580, 11109};

    const ushort_t* vb = value16 + (size_t)b * 256 + h * 32 + d;
    const float* pxr = px_g + (size_t)row * 128 + h * 16;
    const float* pyr = py_g + (size_t)row * 128 + h * 16;
    const float* awr = aw_g + (size_t)row * 128 + h * 16;

    float a0 = 0.f, a1 = 0.f, a2 = 0.f, a3 = 0.f;
#pragma unroll
    for (int l = 0; l < 4; ++l) {
        const int H = HsI[l], W = HsI[l], base = S0_[l];
#pragma unroll
        for (int p = 0; p < 4; ++p) {
            const int lp = l * 4 + p;
            float px = pxr[lp], py = pyr[lp], aw = awr[lp];
            float x0f = floorf(px), y0f = floorf(py);
            int x0 = (int)x0f, y0 = (int)y0f;
            float wx = px - x0f, wy = py - y0f;
            float s0 = 0.f, s1 = 0.f, s2 = 0.f, s3 = 0.f;
#pragma unroll
            for (int dy = 0; dy < 2; ++dy) {
#pragma unroll
                for (int dx = 0; dx < 2; ++dx) {
                    int xi = x0 + dx, yi = y0 + dy;
                    float flag = (xi >= 0 && xi < W && yi >= 0 && yi < H) ? 1.f : 0.f;
                    int xc = xi < 0 ? 0 : (xi >= W ? W - 1 : xi);
                    int yc = yi < 0 ? 0 : (yi >= H ? H - 1 : yi);
                    float wgt = (dx ? wx : 1.f - wx) * (dy ? wy : 1.f - wy) * flag;
                    uint2 gv = *(const uint2*)(vb + (size_t)(base + yc * W + xc) * 1024);
                    s0 = fmaf(wgt, bf2f((ushort_t)(gv.x & 0xffffu)), s0);
                    s1 = fmaf(wgt, bf2f((ushort_t)(gv.x >> 16)), s1);
                    s2 = fmaf(wgt, bf2f((ushort_t)(gv.y & 0xffffu)), s2);
                    s3 = fmaf(wgt, bf2f((ushort_t)(gv.y >> 16)), s3);
                }
            }
            a0 = fmaf(aw, s0, a0);
            a1 = fmaf(aw, s1, a1);
            a2 = fmaf(aw, s2, a2);
            a3 = fmaf(aw, s3, a3);
        }
    }
    uint2 u;
    u.x = pack2bf(a0, a1);
    u.y = pack2bf(a2, a3);
    *(uint2*)(out + (size_t)row * 256 + h * 32 + d) = u;
}

// ---------------------------------------------------------------------------
// ffn_fused (unchanged from R8): oproj2+LN1 + FFN1(relu) + FFN2 + LN3.
// ---------------------------------------------------------------------------
__global__ __launch_bounds__(512, 1) void ffn_fused(
    const ushort_t* __restrict__ att2_16,
    const float* __restrict__ tgt_a,
    const ushort_t* __restrict__ op_wb, const float* __restrict__ op_b,
    const float* __restrict__ ln1g, const float* __restrict__ ln1b,
    const ushort_t* __restrict__ l1_wb, const float* __restrict__ l1b,
    const ushort_t* __restrict__ l2_wb, const float* __restrict__ l2b,
    const float* __restrict__ ln3g, const float* __restrict__ ln3b,
    float* __restrict__ out)
{
    __shared__ ushort_t Ws[2][256 * 64];   // 64 KB
    __shared__ ushort_t A1[16 * 264];      // LN1 output (bf16)
    __shared__ ushort_t hc[16 * 264];      // att2 staging / hidden chunk
    __shared__ float    sS[8][16], s2S[8][16];

    const int t    = threadIdx.x;
    const int m0   = blockIdx.x * 16;
    const int wv   = t >> 6;
    const int ln   = t & 63;
    const int L    = ln & 15;
    const int quad = ln >> 4;
    const int swz  = (L & 7) << 3;
    const int lrow = ln >> 3;
    const int lchk = (ln & 7) << 3;
    const int rloc = quad * 4;

    auto stageWs = [&](const ushort_t* base, int stride, int buf) {
#pragma unroll
        for (int j = 0; j < 4; ++j) {
            int r0 = (wv * 4 + j) * 8;
            stage_w16(base + (size_t)(r0 + lrow) * stride + lchk, &Ws[buf][r0 * 64], ln);
        }
    };
    auto mfma2 = [&](const ushort_t* A, int koff, int buf, f32x4* acc) {
#pragma unroll
        for (int kh = 0; kh < 2; ++kh) {
            int ko = (kh * 32 + quad * 8) ^ swz;
            short8 af = *(const short8*)&A[L * 264 + koff + kh * 32 + quad * 8];
#pragma unroll
            for (int cb = 0; cb < 2; ++cb) {
                short8 bf = *(const short8*)&Ws[buf][(wv * 32 + cb * 16 + L) * 64 + ko];
                acc[cb] = __builtin_amdgcn_mfma_f32_16x16x32_bf16(af, bf, acc[cb], 0, 0, 0);
            }
        }
    };

    // load att2 tile
    {
        int r = t >> 5, s = (t & 31) * 8;
        *(uint4*)&hc[r * 264 + s] = *(const uint4*)(att2_16 + (size_t)(m0 + r) * 256 + s);
    }
    stageWs(op_wb, 256, 0);
    __syncthreads();
    int cur = 0;

    f32x4 resid[2];

    // ---- oproj2 + LN1 ----
    {
        f32x4 acc[2] = {{0.f,0.f,0.f,0.f},{0.f,0.f,0.f,0.f}};
        for (int k = 0; k < 4; ++k) {
            if (k < 3) stageWs(op_wb + (k + 1) * 64, 256, cur ^ 1);
            else       stageWs(l1_wb, 256, cur ^ 1);
            mfma2(hc, k * 64, cur, acc);
            __syncthreads();
            cur ^= 1;
        }
        float s[4] = {0.f,0.f,0.f,0.f}, s2v[4] = {0.f,0.f,0.f,0.f};
#pragma unroll
        for (int cb = 0; cb < 2; ++cb) {
            int col = wv * 32 + cb * 16 + L;
            float bv = op_b[col];
#pragma unroll
            for (int i = 0; i < 4; ++i) {
                float xv = acc[cb][i] + bv + tgt_a[(size_t)(m0 + rloc + i) * 256 + col];
                acc[cb][i] = xv;
                s[i] += xv; s2v[i] += xv * xv;
            }
        }
#pragma unroll
        for (int off = 1; off < 16; off <<= 1)
#pragma unroll
            for (int i = 0; i < 4; ++i) {
                s[i]   += __shfl_xor(s[i],   off, 64);
                s2v[i] += __shfl_xor(s2v[i], off, 64);
            }
        if (L == 0)
#pragma unroll
            for (int i = 0; i < 4; ++i) { sS[wv][rloc + i] = s[i]; s2S[wv][rloc + i] = s2v[i]; }
        __syncthreads();
        float mean[4], rstd[4];
#pragma unroll
        for (int i = 0; i < 4; ++i) {
            float St = 0.f, S2t = 0.f;
#pragma unroll
            for (int w = 0; w < 8; ++w) { St += sS[w][rloc + i]; S2t += s2S[w][rloc + i]; }
            mean[i] = St * (1.f / 256.f);
            float var = S2t * (1.f / 256.f) - mean[i] * mean[i];
            rstd[i] = rsqrtf(var + 1e-5f);
        }
#pragma unroll
        for (int cb = 0; cb < 2; ++cb) {
            int col = wv * 32 + cb * 16 + L;
            float gv = ln1g[col], bt = ln1b[col];
#pragma unroll
            for (int i = 0; i < 4; ++i) {
                float y = (acc[cb][i] - mean[i]) * rstd[i] * gv + bt;
                resid[cb][i] = y;
                A1[(rloc + i) * 264 + col] = (ushort_t)f2bf1(y);
            }
        }
        __syncthreads();
    }

    // ---- FFN1 chunked into FFN2 ----
    f32x4 accf[2] = {{0.f,0.f,0.f,0.f},{0.f,0.f,0.f,0.f}};
    for (int c = 0; c < 4; ++c) {
        f32x4 acch[2] = {{0.f,0.f,0.f,0.f},{0.f,0.f,0.f,0.f}};
        for (int k = 0; k < 4; ++k) {
            if (k < 3) stageWs(l1_wb + (size_t)(c * 256) * 256 + (k + 1) * 64, 256, cur ^ 1);
            else       stageWs(l2_wb + c * 256, 1024, cur ^ 1);
            mfma2(A1, k * 64, cur, acch);
            __syncthreads();
            cur ^= 1;
        }
        // hidden chunk -> hc (relu, bf16)
#pragma unroll
        for (int cb = 0; cb < 2; ++cb) {
            int colc = wv * 32 + cb * 16 + L;
            float bv = l1b[c * 256 + colc];
#pragma unroll
            for (int i = 0; i < 4; ++i)
                hc[(rloc + i) * 264 + colc] = (ushort_t)f2bf1(fmaxf(acch[cb][i] + bv, 0.f));
        }
        __syncthreads();
        for (int k = 0; k < 4; ++k) {
            if (k < 3)      stageWs(l2_wb + c * 256 + (k + 1) * 64, 1024, cur ^ 1);
            else if (c < 3) stageWs(l1_wb + (size_t)((c + 1) * 256) * 256, 256, cur ^ 1);
            mfma2(hc, k * 64, cur, accf);
            __syncthreads();
            cur ^= 1;
        }
    }

    // ---- LN3 -> out ----
    {
        float s[4] = {0.f,0.f,0.f,0.f}, s2v[4] = {0.f,0.f,0.f,0.f};
#pragma unroll
        for (int cb = 0; cb < 2; ++cb) {
            int col = wv * 32 + cb * 16 + L;
            float bv = l2b[col];
#pragma unroll
            for (int i = 0; i < 4; ++i) {
                float xv = accf[cb][i] + bv + resid[cb][i];
                accf[cb][i] = xv;
                s[i] += xv; s2v[i] += xv * xv;
            }
        }
#pragma unroll
        for (int off = 1; off < 16; off <<= 1)
#pragma unroll
            for (int i = 0; i < 4; ++i) {
                s[i]   += __shfl_xor(s[i],   off, 64);
                s2v[i] += __shfl_xor(s2v[i], off, 64);
            }
        if (L == 0)
#pragma unroll
            for (int i = 0; i < 4; ++i) { sS[wv][rloc + i] = s[i]; s2S[wv][rloc + i] = s2v[i]; }
        __syncthreads();
        float mean[4], rstd[4];
#pragma unroll
        for (int i = 0; i < 4; ++i) {
            float St = 0.f, S2t = 0.f;
#pragma unroll
            for (int w = 0; w < 8; ++w) { St += sS[w][rloc + i]; S2t += s2S[w][rloc + i]; }
            mean[i] = St * (1.f / 256.f);
            float var = S2t * (1.f / 256.f) - mean[i] * mean[i];
            rstd[i] = rsqrtf(var + 1e-5f);
        }
#pragma unroll
        for (int cb = 0; cb < 2; ++cb) {
            int col = wv * 32 + cb * 16 + L;
            float gv = ln3g[col], bt = ln3b[col];
#pragma unroll
            for (int i = 0; i < 4; ++i) {
                float y = (accf[cb][i] - mean[i]) * rstd[i] * gv + bt;
                out[(size_t)(m0 + rloc + i) * 256 + col] = y;
            }
        }
    }
}

// ---------------------------------------------------------------------------
extern "C" void kernel_launch(void* const* d_in, const int* in_sizes, int n_in,
                              void* d_out, int out_size, void* d_ws, size_t ws_size,
                              hipStream_t stream)
{
    const float* tgt    = (const float*)d_in[0];
    const float* qpos   = (const float*)d_in[1];
    const float* refp   = (const float*)d_in[2];
    const float* mem    = (const float*)d_in[3];
    const float* in_w   = (const float*)d_in[6];
    const float* in_b   = (const float*)d_in[7];
    const float* outp_w = (const float*)d_in[8];
    const float* outp_b = (const float*)d_in[9];
    const float* off_w  = (const float*)d_in[10];
    const float* off_b  = (const float*)d_in[11];
    const float* aw_w   = (const float*)d_in[12];
    const float* aw_b   = (const float*)d_in[13];
    const float* vp_w   = (const float*)d_in[14];
    const float* vp_b   = (const float*)d_in[15];
    const float* op_w   = (const float*)d_in[16];
    const float* op_b   = (const float*)d_in[17];
    const float* ln1g   = (const float*)d_in[18];
    const float* ln1b   = (const float*)d_in[19];
    const float* ln2g   = (const float*)d_in[20];
    const float* ln2b   = (const float*)d_in[21];
    const float* ln3g   = (const float*)d_in[22];
    const float* ln3b   = (const float*)d_in[23];
    const float* l1w    = (const float*)d_in[24];
    const float* l1b    = (const float*)d_in[25];
    const float* l2w    = (const float*)d_in[26];
    const float* l2b    = (const float*)d_in[27];
    float* out = (float*)d_out;
    float* ws  = (float*)d_ws;

    // workspace layout (float units) — identical to passing R8 layout.
    ushort_t* qkv16    = (ushort_t*)ws;
    ushort_t* att16    = (ushort_t*)(ws + 691200);
    float*    tgt_a    = ws + 1843200;
    ushort_t* tgt16    = (ushort_t*)(ws + 1843200);     // dies before tgt_a written
    ushort_t* tq16     = (ushort_t*)(ws + 2310144);     // ends 2777088 < 2995200
    float*    px_g     = ws + 2995200;
    float*    py_g     = ws + 3456000;
    float*    aw_g     = ws + 3916800;
    ushort_t* att2_16  = (ushort_t*)(ws + 4377600);
    ushort_t* value16  = (ushort_t*)(ws + 5760000);
    ushort_t* wb       = (ushort_t*)(ws + 13364736);    // ends 13872640

    const ushort_t* in_wb   = wb + WB_IN;
    const ushort_t* vp_wb   = wb + WB_VP;
    const ushort_t* outp_wb = wb + WB_OUTP;
    const ushort_t* off_wb  = wb + WB_OFF;
    const ushort_t* aw_wb   = wb + WB_AW;
    const ushort_t* op_wb   = wb + WB_OP;
    const ushort_t* l1_wb   = wb + WB_L1;
    const ushort_t* l2_wb   = wb + WB_L2;

    dim3 b256(256);

    // 0. weights + qkv A-inputs -> bf16 (pre-swizzled)
    hipLaunchKernelGGL(cvt_weights, dim3(1408), b256, 0, stream,
                       in_w, vp_w, outp_w, off_w, aw_w, op_w, l1w, l2w, wb,
                       tgt, qpos, tgt16, tq16);
    // 1. qkv (all-gll, dbuf) + value projection (gll W dbuf, converted A dbuf)
    hipLaunchKernelGGL(proj_fused, dim3(1388), b256, 0, stream,
                       tq16, tgt16, in_wb, in_b, mem, vp_wb, vp_b, qkv16, value16);
    // 2. flash self-attention
    hipLaunchKernelGGL(sa_flash16, dim3(15, 32), b256, 0, stream, qkv16, att16);
    // 3. oproj + LN2 + off/aw GEMMs + softmax + coords (dbuf, 512 thr)
    hipLaunchKernelGGL(fused_ca, dim3(225), dim3(512), 0, stream,
                       att16, tgt, qpos, outp_wb, outp_b, ln2g, ln2b,
                       off_wb, off_b, aw_wb, aw_b, refp,
                       tgt_a, px_g, py_g, aw_g);
    // 4. deformable sampling (vectorized 4x)
    hipLaunchKernelGGL(msdeform4, dim3(900), b256, 0, stream,
                       px_g, py_g, aw_g, value16, att2_16);
    // 5. oproj2 + LN1 + FFN1 + FFN2 + LN3 (dbuf, 512 thr)
    hipLaunchKernelGGL(ffn_fused, dim3(225), dim3(512), 0, stream,
                       att2_16, tgt_a, op_wb, op_b, ln1g, ln1b,
                       l1_wb, l1b, l2_wb, l2b, ln3g, ln3b, out);
}

// Round 10
// 242.940 us; speedup vs baseline: 1.0233x; 1.0233x over previous
//
#include <hip/hip_runtime.h>
#include <math.h>

#define D_MODEL 256
#define NHEAD   8
#define NLVL    4
#define NPTS    4
#define DHEAD   32
#define DFFN    1024
#define NQ      900
#define BSZ     4
#define NROW    (NQ * BSZ)      // 3600
#define NROWP   3648            // padded to 57*64
#define S_TOT   11253
#define VROWS   (S_TOT * BSZ)   // 45012
#define SASCALE 0.17677669529663687f

typedef __attribute__((ext_vector_type(8))) short short8;
typedef __attribute__((ext_vector_type(4))) float f32x4;
typedef unsigned short ushort_t;

static __device__ __forceinline__ unsigned f2bf1(float f) {
    unsigned u = __float_as_uint(f);
    return (u + 0x7FFFu + ((u >> 16) & 1u)) >> 16;
}
static __device__ __forceinline__ unsigned pack2bf(float x, float y) {
    return f2bf1(x) | (f2bf1(y) << 16);
}
static __device__ __forceinline__ float bf2f(ushort_t u) {
    return __uint_as_float(((unsigned)u) << 16);
}

#if __has_builtin(__builtin_amdgcn_global_load_lds)
#define HAS_GLL 1
#endif

static __device__ __forceinline__ void stage_w16(const ushort_t* g, ushort_t* ldsbase, int lane)
{
#ifdef HAS_GLL
    __builtin_amdgcn_global_load_lds(
        (const __attribute__((address_space(1))) unsigned int*)g,
        (__attribute__((address_space(3))) unsigned int*)ldsbase, 16, 0, 0);
#else
    *(uint4*)(ldsbase + lane * 8) = *(const uint4*)g;
#endif
}

// T4 counted-vmcnt barrier: allow the N newest (this phase's prefetch) to stay
// in flight; everything older (the tile about to be consumed) is complete.
// lgkmcnt(0) makes ds_write staging visible; sched_barrier pins ordering (#18).
#define WAIT_VM_BAR(N) do {                                            \
    asm volatile("s_waitcnt vmcnt(" #N ") lgkmcnt(0)" ::: "memory");   \
    __builtin_amdgcn_sched_barrier(0);                                 \
    __builtin_amdgcn_s_barrier(); } while (0)

// LDS-visibility-only barrier (keeps weight prefetch loads in flight).
#define LK_BAR() do {                                                  \
    asm volatile("s_waitcnt lgkmcnt(0)" ::: "memory");                 \
    __builtin_amdgcn_sched_barrier(0);                                 \
    __builtin_amdgcn_s_barrier(); } while (0)

// bf16 weight buffer element offsets
#define WB_IN   0         // 768*256
#define WB_VP   196608    // 256*256
#define WB_OUTP 262144    // 256*256
#define WB_OFF  327680    // 256*256
#define WB_AW   393216    // 128*256
#define WB_OP   425984    // 256*256
#define WB_L1   491520    // 1024*256
#define WB_L2   753664    // 256*1024
#define WB_TOT  1015808

// ---------------------------------------------------------------------------
// cvt_weights: weights (pre-swizzled) + qkv A-input pre-conversion.
// Swizzle: k' = (k & ~63) | ((k&63) ^ ((row&7)<<3)).
// ---------------------------------------------------------------------------
__global__ __launch_bounds__(256) void cvt_weights(
    const float* __restrict__ w_in, const float* __restrict__ w_vp,
    const float* __restrict__ w_outp, const float* __restrict__ w_off,
    const float* __restrict__ w_aw, const float* __restrict__ w_op,
    const float* __restrict__ w_l1, const float* __restrict__ w_l2,
    ushort_t* __restrict__ dst,
    const float* __restrict__ tgt, const float* __restrict__ qpos,
    ushort_t* __restrict__ tgt16, ushort_t* __restrict__ tq16)
{
    int b = blockIdx.x;
    if (b < 496) {
        const float* src;
        int dstoff;
        int kbits = 8;
        if (b < 96)       { src = w_in;   dstoff = WB_IN;   }
        else if (b < 128) { src = w_vp;   b -= 96;  dstoff = WB_VP;   }
        else if (b < 160) { src = w_outp; b -= 128; dstoff = WB_OUTP; }
        else if (b < 192) { src = w_off;  b -= 160; dstoff = WB_OFF;  }
        else if (b < 208) { src = w_aw;   b -= 192; dstoff = WB_AW;   }
        else if (b < 240) { src = w_op;   b -= 208; dstoff = WB_OP;   }
        else if (b < 368) { src = w_l1;   b -= 240; dstoff = WB_L1;   }
        else              { src = w_l2;   b -= 368; dstoff = WB_L2;   kbits = 10; }
        int i = (b * 256 + threadIdx.x) * 8;
        float4 f0 = *(const float4*)(src + i);
        float4 f1 = *(const float4*)(src + i + 4);
        uint4 u;
        u.x = pack2bf(f0.x, f0.y); u.y = pack2bf(f0.z, f0.w);
        u.z = pack2bf(f1.x, f1.y); u.w = pack2bf(f1.z, f1.w);
        int K = 1 << kbits;
        int n = i >> kbits;
        int k = i & (K - 1);
        int kswz = (k & ~63) | ((k & 63) ^ ((n & 7) << 3));
        *(uint4*)(dst + dstoff + (size_t)n * K + kswz) = u;
    } else {
        int bb = b - 496;
        ushort_t* dbuf = tgt16;
        bool addq = false;
        if (bb >= 456) { bb -= 456; dbuf = tq16; addq = true; }
        int i = bb * 2048 + threadIdx.x * 8;     // < 933888 (exact, no tail)
        int row = i >> 8, k = i & 255;
        uint4 u = make_uint4(0u, 0u, 0u, 0u);
        if (row < NROW) {
            const float* sp = tgt + (size_t)row * 256 + k;
            float4 f0 = *(const float4*)(sp + 0);
            float4 f1 = *(const float4*)(sp + 4);
            if (addq) {
                const float* qp = qpos + (size_t)row * 256 + k;
                float4 q0 = *(const float4*)(qp + 0);
                float4 q1 = *(const float4*)(qp + 4);
                f0.x += q0.x; f0.y += q0.y; f0.z += q0.z; f0.w += q0.w;
                f1.x += q1.x; f1.y += q1.y; f1.z += q1.z; f1.w += q1.w;
            }
            u.x = pack2bf(f0.x, f0.y); u.y = pack2bf(f0.z, f0.w);
            u.z = pack2bf(f1.x, f1.y); u.w = pack2bf(f1.z, f1.w);
        }
        int kswz = (k & ~63) | ((k & 63) ^ ((row & 7) << 3));
        *(uint4*)(dbuf + (size_t)row * 256 + kswz) = u;
    }
}

// ---------------------------------------------------------------------------
// proj_fused (R20): dbuf + counted-vmcnt (T3+T4) schedule.
// Per phase: stage(k+1 -> buf^1); vmcnt(N)+lgkm(0)+barrier; MFMA(k, buf);
// barrier. The drain-to-0 that made R9's dbuf a no-op is gone.
// ---------------------------------------------------------------------------
__global__ __launch_bounds__(256) void proj_fused(
    const ushort_t* __restrict__ tq16, const ushort_t* __restrict__ tgt16,
    const ushort_t* __restrict__ in_wb, const float* __restrict__ in_b,
    const float* __restrict__ mem, const ushort_t* __restrict__ vp_wb,
    const float* __restrict__ vp_b,
    ushort_t* __restrict__ qkv16, ushort_t* __restrict__ value16)
{
    __shared__ ushort_t As[2][64 * 64];   // 16 KB
    __shared__ ushort_t Ws[2][256 * 64];  // 64 KB (qkv uses rows 0..63)

    const int t    = threadIdx.x;
    const int bid  = blockIdx.x;
    const int wv   = t >> 6;
    const int ln   = t & 63;
    const int L    = ln & 15;
    const int quad = ln >> 4;
    const int swz  = (L & 7) << 3;
    const int lrow = ln >> 3;
    const int lchk = (ln & 7) << 3;

    if (bid < 684) {
        const int m0 = (bid % 57) * 64;
        const int n0 = (bid / 57) * 64;
        const float oscale = (n0 < 256) ? SASCALE : 1.f;
        const ushort_t* Ab = (n0 < 512) ? tq16 : tgt16;

        auto stageQ = [&](int k0, int buf) {   // 4 gll per wave
#pragma unroll
            for (int j = 0; j < 2; ++j) {
                int r0 = (wv * 2 + j) * 8;
                stage_w16(Ab + (size_t)(m0 + r0 + lrow) * 256 + k0 + lchk, &As[buf][r0 * 64], ln);
                stage_w16(in_wb + (size_t)(n0 + r0 + lrow) * 256 + k0 + lchk, &Ws[buf][r0 * 64], ln);
            }
        };

        f32x4 acc[4] = {{0.f,0.f,0.f,0.f},{0.f,0.f,0.f,0.f},
                        {0.f,0.f,0.f,0.f},{0.f,0.f,0.f,0.f}};

        stageQ(0, 0);
        int cur = 0;
        for (int k = 0; k < 4; ++k) {
            if (k < 3) { stageQ((k + 1) * 64, cur ^ 1); WAIT_VM_BAR(4); }
            else       { WAIT_VM_BAR(0); }
#pragma unroll
            for (int kh = 0; kh < 2; ++kh) {
                int ko = (kh * 32 + quad * 8) ^ swz;
                short8 af = *(const short8*)&As[cur][(wv * 16 + L) * 64 + ko];
#pragma unroll
                for (int cb = 0; cb < 4; ++cb) {
                    short8 bf = *(const short8*)&Ws[cur][(cb * 16 + L) * 64 + ko];
                    acc[cb] = __builtin_amdgcn_mfma_f32_16x16x32_bf16(af, bf, acc[cb], 0, 0, 0);
                }
            }
            __builtin_amdgcn_s_barrier();
            cur ^= 1;
        }
#pragma unroll
        for (int cb = 0; cb < 4; ++cb) {
            int col = n0 + cb * 16 + L;
            float bv = in_b[col];
#pragma unroll
            for (int i = 0; i < 4; ++i) {
                int m = m0 + wv * 16 + quad * 4 + i;
                if (m < NROW)
                    qkv16[(size_t)m * 768 + col] = (ushort_t)f2bf1((acc[cb][i] + bv) * oscale);
            }
        }
    } else {
        const int vb = bid - 684;        // 0..703
        const int m0 = vb * 64;
        const int trow = t >> 2;
        const int tk   = (t & 3) << 4;
        const int wsz  = (trow & 7) << 3;    // write-side swizzle

        const int  mrow = m0 + trow;
        const bool mv   = (mrow < VROWS);
        const float* arow = mem + (size_t)mrow * 256 + tk;

        auto stageWv = [&](int k0, int buf) {   // 8 gll per wave
#pragma unroll
            for (int j = 0; j < 8; ++j) {
                int r0 = (wv * 8 + j) * 8;
                stage_w16(vp_wb + (size_t)(r0 + lrow) * 256 + k0 + lchk, &Ws[buf][r0 * 64], ln);
            }
        };
        auto stageAv = [&](int k0, int buf) {   // reg path; loads retire in-wave
            uint4 u0, u1;
            if (mv) {
                const float* ap = arow + k0;
                float4 a0 = *(const float4*)(ap + 0);
                float4 a1 = *(const float4*)(ap + 4);
                float4 a2 = *(const float4*)(ap + 8);
                float4 a3 = *(const float4*)(ap + 12);
                u0.x = pack2bf(a0.x, a0.y); u0.y = pack2bf(a0.z, a0.w);
                u0.z = pack2bf(a1.x, a1.y); u0.w = pack2bf(a1.z, a1.w);
                u1.x = pack2bf(a2.x, a2.y); u1.y = pack2bf(a2.z, a2.w);
                u1.z = pack2bf(a3.x, a3.y); u1.w = pack2bf(a3.z, a3.w);
            } else {
                u0 = make_uint4(0u, 0u, 0u, 0u); u1 = u0;
            }
            *(uint4*)&As[buf][trow * 64 + (tk ^ wsz)]       = u0;
            *(uint4*)&As[buf][trow * 64 + ((tk + 8) ^ wsz)] = u1;
        };

        f32x4 acc[16];
#pragma unroll
        for (int i = 0; i < 16; ++i) acc[i] = (f32x4){0.f, 0.f, 0.f, 0.f};

        stageWv(0, 0);
        stageAv(0, 0);
        int cur = 0;
        for (int k = 0; k < 4; ++k) {
            if (k < 3) { stageWv((k + 1) * 64, cur ^ 1); WAIT_VM_BAR(8); }
            else       { WAIT_VM_BAR(0); }
#pragma unroll
            for (int kh = 0; kh < 2; ++kh) {
                int ko = (kh * 32 + quad * 8) ^ swz;
                short8 af = *(const short8*)&As[cur][(wv * 16 + L) * 64 + ko];
#pragma unroll
                for (int cb = 0; cb < 16; ++cb) {
                    short8 bf = *(const short8*)&Ws[cur][(cb * 16 + L) * 64 + ko];
                    acc[cb] = __builtin_amdgcn_mfma_f32_16x16x32_bf16(af, bf, acc[cb], 0, 0, 0);
                }
            }
            if (k < 3) stageAv((k + 1) * 64, cur ^ 1);   // hides under MFMAs
            __builtin_amdgcn_s_barrier();
            cur ^= 1;
        }

        // epilogue: bias + bf16, repack through LDS (two 128-col passes)
        ushort_t* Cs = Ws[0];   // 64 rows x 136 stride = 17408 B <= 32 KB
#pragma unroll
        for (int half = 0; half < 2; ++half) {
            if (half) __syncthreads();
#pragma unroll
            for (int cb = 0; cb < 8; ++cb) {
                int col = cb * 16 + L;
                float bv = vp_b[half * 128 + col];
#pragma unroll
                for (int i = 0; i < 4; ++i) {
                    int r = wv * 16 + quad * 4 + i;
                    Cs[r * 136 + col] = (ushort_t)f2bf1(acc[half * 8 + cb][i] + bv);
                }
            }
            __syncthreads();
            {
                int r  = t >> 2;
                int ch = (t & 3) * 32;
                int m  = m0 + r;
                if (m < VROWS) {
                    const ushort_t* src = &Cs[r * 136 + ch];
                    uint4* dst = (uint4*)(value16 + (size_t)m * 256 + half * 128 + ch);
#pragma unroll
                    for (int j = 0; j < 4; ++j)
                        dst[j] = *(const uint4*)(src + j * 8);
                }
            }
        }
    }
}

// ---------------------------------------------------------------------------
// MFMA flash self-attention (unchanged).
// ---------------------------------------------------------------------------
__global__ __launch_bounds__(256) void sa_flash16(
    const ushort_t* __restrict__ qkv, ushort_t* __restrict__ attn_out)
{
    __shared__ ushort_t Ks[2 * 2080];
    __shared__ ushort_t Vt[2 * 2304];
    __shared__ ushort_t Ps[4 * 1152];

    const int t    = threadIdx.x;
    const int q0   = blockIdx.x * 64;
    const int b    = blockIdx.y & 3;
    const int h    = blockIdx.y >> 2;
    const int wv   = t >> 6;
    const int ln   = t & 63;
    const int L    = ln & 15;
    const int quad = ln >> 4;

    union { uint4 u; short8 s; } qu;
    qu.u = make_uint4(0u, 0u, 0u, 0u);
    {
        int q = q0 + wv * 16 + L;
        if (q < NQ)
            qu.u = *(const uint4*)(qkv + ((size_t)q * 4 + b) * 768 + h * 32 + quad * 8);
    }
    const short8 qf = qu.s;

    float mrun = -1e30f, lrun = 0.f;
    f32x4 oacc[2] = {{0.f,0.f,0.f,0.f},{0.f,0.f,0.f,0.f}};

    const int skey = t >> 2;
    const int sdg  = t & 3;

    uint4 ku, vu;
    auto kv_load = [&](int k0) {
        int kg = k0 + skey;
        ku = make_uint4(0u, 0u, 0u, 0u);
        vu = make_uint4(0u, 0u, 0u, 0u);
        if (kg < NQ) {
            const ushort_t* base = qkv + ((size_t)kg * 4 + b) * 768 + 256 + h * 32 + sdg * 8;
            ku = *(const uint4*)base;
            vu = *(const uint4*)(base + 256);
        }
    };

    kv_load(0);
    int it = 0;
    for (int k0 = 0; k0 < NQ; k0 += 64, it ^= 1) {
        *(uint4*)&Ks[it * 2080 + sdg * 520 + skey * 8] = ku;
        {
            ushort_t* vp = &Vt[it * 2304 + sdg * 8 * 72 + skey];
            vp[0 * 72] = (ushort_t)(vu.x & 0xffffu);
            vp[1 * 72] = (ushort_t)(vu.x >> 16);
            vp[2 * 72] = (ushort_t)(vu.y & 0xffffu);
            vp[3 * 72] = (ushort_t)(vu.y >> 16);
            vp[4 * 72] = (ushort_t)(vu.z & 0xffffu);
            vp[5 * 72] = (ushort_t)(vu.z >> 16);
            vp[6 * 72] = (ushort_t)(vu.w & 0xffffu);
            vp[7 * 72] = (ushort_t)(vu.w >> 16);
        }
        __syncthreads();
        if (k0 + 64 < NQ) kv_load(k0 + 64);

        f32x4 sacc[4] = {{0.f,0.f,0.f,0.f},{0.f,0.f,0.f,0.f},
                         {0.f,0.f,0.f,0.f},{0.f,0.f,0.f,0.f}};
#pragma unroll
        for (int cb = 0; cb < 4; ++cb) {
            short8 kf = *(const short8*)&Ks[it * 2080 + quad * 520 + (cb * 16 + L) * 8];
            sacc[cb] = __builtin_amdgcn_mfma_f32_16x16x32_bf16(kf, qf, sacc[cb], 0, 0, 0);
        }
        if (k0 + 64 > NQ) {
#pragma unroll
            for (int cb = 0; cb < 4; ++cb)
#pragma unroll
                for (int i = 0; i < 4; ++i)
                    if (k0 + cb * 16 + quad * 4 + i >= NQ) sacc[cb][i] = -1e30f;
        }

        float ml = -1e30f;
#pragma unroll
        for (int cb = 0; cb < 4; ++cb)
#pragma unroll
            for (int i = 0; i < 4; ++i) ml = fmaxf(ml, sacc[cb][i]);
        ml = fmaxf(ml, __shfl_xor(ml, 16, 64));
        ml = fmaxf(ml, __shfl_xor(ml, 32, 64));
        float mnew  = fmaxf(mrun, ml);
        float alpha = __expf(mrun - mnew);
        float p[16];
        float rs = 0.f;
#pragma unroll
        for (int cb = 0; cb < 4; ++cb)
#pragma unroll
            for (int i = 0; i < 4; ++i) {
                float e = __expf(sacc[cb][i] - mnew);
                p[cb * 4 + i] = e;
                rs += e;
            }
        rs += __shfl_xor(rs, 16, 64);
        rs += __shfl_xor(rs, 32, 64);
        lrun = lrun * alpha + rs;
        mrun = mnew;

        {
            ushort_t* pw = &Ps[wv * 1152 + L * 72];
#pragma unroll
            for (int cb = 0; cb < 4; ++cb) {
                uint2 u;
                u.x = pack2bf(p[cb * 4 + 0], p[cb * 4 + 1]);
                u.y = pack2bf(p[cb * 4 + 2], p[cb * 4 + 3]);
                *(uint2*)&pw[cb * 16 + quad * 4] = u;
            }
        }
#pragma unroll
        for (int i = 0; i < 4; ++i) {
            float ai = __shfl(alpha, quad * 4 + i, 64);
            oacc[0][i] *= ai;
            oacc[1][i] *= ai;
        }
        __syncthreads();

#pragma unroll
        for (int ks = 0; ks < 2; ++ks) {
            short8 pf = *(const short8*)&Ps[wv * 1152 + L * 72 + ks * 32 + quad * 8];
#pragma unroll
            for (int db = 0; db < 2; ++db) {
                short8 vf = *(const short8*)&Vt[it * 2304 + (db * 16 + L) * 72 + ks * 32 + quad * 8];
                oacc[db] = __builtin_amdgcn_mfma_f32_16x16x32_bf16(pf, vf, oacc[db], 0, 0, 0);
            }
        }
    }

#pragma unroll
    for (int i = 0; i < 4; ++i) {
        float lq = __shfl(lrun, quad * 4 + i, 64);
        float li = 1.f / lq;
        int q = q0 + wv * 16 + quad * 4 + i;
        if (q < NQ) {
            ushort_t* op = attn_out + ((size_t)q * 4 + b) * 256 + h * 32 + L;
            op[0]  = (ushort_t)f2bf1(oacc[0][i] * li);
            op[16] = (ushort_t)f2bf1(oacc[1][i] * li);
        }
    }
}

// ---------------------------------------------------------------------------
// fused_ca (R20): dbuf + counted-vmcnt schedule.
// ---------------------------------------------------------------------------
__global__ __launch_bounds__(512, 1) void fused_ca(
    const ushort_t* __restrict__ att16,
    const float* __restrict__ tgt, const float* __restrict__ qpos,
    const ushort_t* __restrict__ outp_wb, const float* __restrict__ outp_b,
    const float* __restrict__ ln2g, const float* __restrict__ ln2b,
    const ushort_t* __restrict__ off_wb, const float* __restrict__ off_b,
    const ushort_t* __restrict__ aw_wb, const float* __restrict__ aw_b,
    const float* __restrict__ refp,
    float* __restrict__ tgt_a, float* __restrict__ px_g,
    float* __restrict__ py_g, float* __restrict__ aw_g)
{
    __shared__ ushort_t Ws[2][256 * 64];   // 64 KB
    __shared__ ushort_t att_s[16 * 264];
    __shared__ ushort_t xca_s[16 * 264];
    __shared__ float    aws_s[16 * 128];
    __shared__ float    sS[8][16], s2S[8][16];

    const int t    = threadIdx.x;
    const int m0   = blockIdx.x * 16;
    const int wv   = t >> 6;       // 0..7
    const int ln   = t & 63;
    const int L    = ln & 15;
    const int quad = ln >> 4;
    const int swz  = (L & 7) << 3;
    const int lrow = ln >> 3;
    const int lchk = (ln & 7) << 3;
    const int rloc = quad * 4;

    auto stage4 = [&](const ushort_t* base, int buf) {   // 4 gll per wave
#pragma unroll
        for (int j = 0; j < 4; ++j) {
            int r0 = (wv * 4 + j) * 8;
            stage_w16(base + (size_t)(r0 + lrow) * 256 + lchk, &Ws[buf][r0 * 64], ln);
        }
    };
    auto stage2 = [&](const ushort_t* base, int buf) {   // 2 gll per wave
#pragma unroll
        for (int j = 0; j < 2; ++j) {
            int r0 = (wv * 2 + j) * 8;
            stage_w16(base + (size_t)(r0 + lrow) * 256 + lchk, &Ws[buf][r0 * 64], ln);
        }
    };
    auto mfma2 = [&](const ushort_t* A, int koff, int buf, f32x4* acc) {
#pragma unroll
        for (int kh = 0; kh < 2; ++kh) {
            int ko = (kh * 32 + quad * 8) ^ swz;
            short8 af = *(const short8*)&A[L * 264 + koff + kh * 32 + quad * 8];
#pragma unroll
            for (int cb = 0; cb < 2; ++cb) {
                short8 bf = *(const short8*)&Ws[buf][(wv * 32 + cb * 16 + L) * 64 + ko];
                acc[cb] = __builtin_amdgcn_mfma_f32_16x16x32_bf16(af, bf, acc[cb], 0, 0, 0);
            }
        }
    };

    // load att16 tile (16x256 bf16 = 8 KB, one uint4 per thread)
    {
        int r = t >> 5, s = (t & 31) * 8;
        *(uint4*)&att_s[r * 264 + s] = *(const uint4*)(att16 + (size_t)(m0 + r) * 256 + s);
    }
    stage4(outp_wb, 0);
    int cur = 0;

    // ---- oproj + LN2 ----
    {
        f32x4 acc[2] = {{0.f,0.f,0.f,0.f},{0.f,0.f,0.f,0.f}};
        for (int k = 0; k < 4; ++k) {
            if (k < 3) stage4(outp_wb + (k + 1) * 64, cur ^ 1);
            else       stage4(off_wb, cur ^ 1);
            WAIT_VM_BAR(4);
            mfma2(att_s, k * 64, cur, acc);
            __builtin_amdgcn_s_barrier();
            cur ^= 1;
        }
        float s[4] = {0.f,0.f,0.f,0.f}, s2v[4] = {0.f,0.f,0.f,0.f};
#pragma unroll
        for (int cb = 0; cb < 2; ++cb) {
            int col = wv * 32 + cb * 16 + L;
            float bv = outp_b[col];
#pragma unroll
            for (int i = 0; i < 4; ++i) {
                float xv = acc[cb][i] + bv + tgt[(size_t)(m0 + rloc + i) * 256 + col];
                acc[cb][i] = xv;
                s[i] += xv; s2v[i] += xv * xv;
            }
        }
#pragma unroll
        for (int off = 1; off < 16; off <<= 1)
#pragma unroll
            for (int i = 0; i < 4; ++i) {
                s[i]   += __shfl_xor(s[i],   off, 64);
                s2v[i] += __shfl_xor(s2v[i], off, 64);
            }
        if (L == 0)
#pragma unroll
            for (int i = 0; i < 4; ++i) { sS[wv][rloc + i] = s[i]; s2S[wv][rloc + i] = s2v[i]; }
        LK_BAR();
        float mean[4], rstd[4];
#pragma unroll
        for (int i = 0; i < 4; ++i) {
            float St = 0.f, S2t = 0.f;
#pragma unroll
            for (int w = 0; w < 8; ++w) { St += sS[w][rloc + i]; S2t += s2S[w][rloc + i]; }
            mean[i] = St * (1.f / 256.f);
            float var = S2t * (1.f / 256.f) - mean[i] * mean[i];
            rstd[i] = rsqrtf(var + 1e-5f);
        }
#pragma unroll
        for (int cb = 0; cb < 2; ++cb) {
            int col = wv * 32 + cb * 16 + L;
            float gv = ln2g[col], bt = ln2b[col];
#pragma unroll
            for (int i = 0; i < 4; ++i) {
                float y = (acc[cb][i] - mean[i]) * rstd[i] * gv + bt;
                tgt_a[(size_t)(m0 + rloc + i) * 256 + col] = y;
                xca_s[(rloc + i) * 264 + col] =
                    (ushort_t)f2bf1(y + qpos[(size_t)(m0 + rloc + i) * 256 + col]);
            }
        }
        // xca_s visibility handled by the next loop's WAIT_VM_BAR (lgkmcnt 0)
    }

    // ---- sampling-offset GEMM -> px/py ----
    {
        f32x4 acc[2] = {{0.f,0.f,0.f,0.f},{0.f,0.f,0.f,0.f}};
        for (int k = 0; k < 4; ++k) {
            if (k < 3) { stage4(off_wb + (k + 1) * 64, cur ^ 1); WAIT_VM_BAR(4); }
            else       { stage2(aw_wb, cur ^ 1);                 WAIT_VM_BAR(2); }
            mfma2(xca_s, k * 64, cur, acc);
            __builtin_amdgcn_s_barrier();
            cur ^= 1;
        }
        const float dims[4] = {92.f, 46.f, 23.f, 12.f};
#pragma unroll
        for (int cb = 0; cb < 2; ++cb) {
            int col = wv * 32 + cb * 16 + L;
            float bv = off_b[col];
            int hh = col >> 5, lp = (col & 31) >> 1, isY = col & 1;
            int l = lp >> 2;
            float dim = dims[l];
            float* dst = isY ? py_g : px_g;
#pragma unroll
            for (int i = 0; i < 4; ++i) {
                int row = m0 + rloc + i;
                float ref = refp[((size_t)row * 4 + l) * 2 + isY];
                dst[(size_t)row * 128 + hh * 16 + lp] = ref * dim + (acc[cb][i] + bv) - 0.5f;
            }
        }
    }

    // ---- attention-weight GEMM (N=128) ----
    {
        f32x4 acc = {0.f, 0.f, 0.f, 0.f};
        for (int k = 0; k < 4; ++k) {
            if (k < 3) { stage2(aw_wb + (k + 1) * 64, cur ^ 1); WAIT_VM_BAR(2); }
            else       { WAIT_VM_BAR(0); }
#pragma unroll
            for (int kh = 0; kh < 2; ++kh) {
                int ko = (kh * 32 + quad * 8) ^ swz;
                short8 af = *(const short8*)&xca_s[L * 264 + k * 64 + kh * 32 + quad * 8];
                short8 bf = *(const short8*)&Ws[cur][(wv * 16 + L) * 64 + ko];
                acc = __builtin_amdgcn_mfma_f32_16x16x32_bf16(af, bf, acc, 0, 0, 0);
            }
            __builtin_amdgcn_s_barrier();
            cur ^= 1;
        }
        {
            int col = wv * 16 + L;
            float bv = aw_b[col];
#pragma unroll
            for (int i = 0; i < 4; ++i)
                aws_s[(rloc + i) * 128 + col] = acc[i] + bv;
        }
        LK_BAR();
    }

    // ---- softmax -> aw_g ----
    if (t < 128) {
        int r = t >> 3, hh = t & 7;
        float v[16];
        float m = -1e30f;
#pragma unroll
        for (int j = 0; j < 16; ++j) { v[j] = aws_s[r * 128 + hh * 16 + j]; m = fmaxf(m, v[j]); }
        float ssum = 0.f;
#pragma unroll
        for (int j = 0; j < 16; ++j) { v[j] = __expf(v[j] - m); ssum += v[j]; }
        float inv = 1.f / ssum;
#pragma unroll
        for (int j = 0; j < 16; ++j)
            aw_g[(size_t)(m0 + r) * 128 + hh * 16 + j] = v[j] * inv;
    }
}

// ---------------------------------------------------------------------------
// msdeform4: deformable sampling, d-vectorized 4x (unchanged).
// ---------------------------------------------------------------------------
__global__ __launch_bounds__(256) void msdeform4(
    const float* __restrict__ px_g, const float* __restrict__ py_g,
    const float* __restrict__ aw_g, const ushort_t* __restrict__ value16,
    ushort_t* __restrict__ out)
{
    const int t   = threadIdx.x;
    const int row = blockIdx.x * 4 + (t >> 6);
    const int ln  = t & 63;
    const int h   = ln >> 3;
    const int d   = (ln & 7) * 4;
    const int b   = row & 3;

    const int HsI[4] = {92, 46, 23, 12};
    const int S0_[4] = {0, 8464, 10580, 11109};

    const ushort_t* vb = value16 + (size_t)b * 256 + h * 32 + d;
    const float* pxr = px_g + (size_t)row * 128 + h * 16;
    const float* pyr = py_g + (size_t)row * 128 + h * 16;
    const float* awr = aw_g + (size_t)row * 128 + h * 16;

    float a0 = 0.f, a1 = 0.f, a2 = 0.f, a3 = 0.f;
#pragma unroll
    for (int l = 0; l < 4; ++l) {
        const int H = HsI[l], W = HsI[l], base = S0_[l];
#pragma unroll
        for (int p = 0; p < 4; ++p) {
            const int lp = l * 4 + p;
            float px = pxr[lp], py = pyr[lp], aw = awr[lp];
            float x0f = floorf(px), y0f = floorf(py);
            int x0 = (int)x0f, y0 = (int)y0f;
            float wx = px - x0f, wy = py - y0f;
            float s0 = 0.f, s1 = 0.f, s2 = 0.f, s3 = 0.f;
#pragma unroll
            for (int dy = 0; dy < 2; ++dy) {
#pragma unroll
                for (int dx = 0; dx < 2; ++dx) {
                    int xi = x0 + dx, yi = y0 + dy;
                    float flag = (xi >= 0 && xi < W && yi >= 0 && yi < H) ? 1.f : 0.f;
                    int xc = xi < 0 ? 0 : (xi >= W ? W - 1 : xi);
                    int yc = yi < 0 ? 0 : (yi >= H ? H - 1 : yi);
                    float wgt = (dx ? wx : 1.f - wx) * (dy ? wy : 1.f - wy) * flag;
                    uint2 gv = *(const uint2*)(vb + (size_t)(base + yc * W + xc) * 1024);
                    s0 = fmaf(wgt, bf2f((ushort_t)(gv.x & 0xffffu)), s0);
                    s1 = fmaf(wgt, bf2f((ushort_t)(gv.x >> 16)), s1);
                    s2 = fmaf(wgt, bf2f((ushort_t)(gv.y & 0xffffu)), s2);
                    s3 = fmaf(wgt, bf2f((ushort_t)(gv.y >> 16)), s3);
                }
            }
            a0 = fmaf(aw, s0, a0);
            a1 = fmaf(aw, s1, a1);
            a2 = fmaf(aw, s2, a2);
            a3 = fmaf(aw, s3, a3);
        }
    }
    uint2 u;
    u.x = pack2bf(a0, a1);
    u.y = pack2bf(a2, a3);
    *(uint2*)(out + (size_t)row * 256 + h * 32 + d) = u;
}

// ---------------------------------------------------------------------------
// ffn_fused (R20): dbuf + counted-vmcnt schedule.
// ---------------------------------------------------------------------------
__global__ __launch_bounds__(512, 1) void ffn_fused(
    const ushort_t* __restrict__ att2_16,
    const float* __restrict__ tgt_a,
    const ushort_t* __restrict__ op_wb, const float* __restrict__ op_b,
    const float* __restrict__ ln1g, const float* __restrict__ ln1b,
    const ushort_t* __restrict__ l1_wb, const float* __restrict__ l1b,
    const ushort_t* __restrict__ l2_wb, const float* __restrict__ l2b,
    const float* __restrict__ ln3g, const float* __restrict__ ln3b,
    float* __restrict__ out)
{
    __shared__ ushort_t Ws[2][256 * 64];   // 64 KB
    __shared__ ushort_t A1[16 * 264];      // LN1 output (bf16)
    __shared__ ushort_t hc[16 * 264];      // att2 staging / hidden chunk
    __shared__ float    sS[8][16], s2S[8][16];

    const int t    = threadIdx.x;
    const int m0   = blockIdx.x * 16;
    const int wv   = t >> 6;
    const int ln   = t & 63;
    const int L    = ln & 15;
    const int quad = ln >> 4;
    const int swz  = (L & 7) << 3;
    const int lrow = ln >> 3;
    const int lchk = (ln & 7) << 3;
    const int rloc = quad * 4;

    auto stageWs = [&](const ushort_t* base, int stride, int buf) {   // 4 gll/wave
#pragma unroll
        for (int j = 0; j < 4; ++j) {
            int r0 = (wv * 4 + j) * 8;
            stage_w16(base + (size_t)(r0 + lrow) * stride + lchk, &Ws[buf][r0 * 64], ln);
        }
    };
    auto mfma2 = [&](const ushort_t* A, int koff, int buf, f32x4* acc) {
#pragma unroll
        for (int kh = 0; kh < 2; ++kh) {
            int ko = (kh * 32 + quad * 8) ^ swz;
            short8 af = *(const short8*)&A[L * 264 + koff + kh * 32 + quad * 8];
#pragma unroll
            for (int cb = 0; cb < 2; ++cb) {
                short8 bf = *(const short8*)&Ws[buf][(wv * 32 + cb * 16 + L) * 64 + ko];
                acc[cb] = __builtin_amdgcn_mfma_f32_16x16x32_bf16(af, bf, acc[cb], 0, 0, 0);
            }
        }
    };

    // load att2 tile
    {
        int r = t >> 5, s = (t & 31) * 8;
        *(uint4*)&hc[r * 264 + s] = *(const uint4*)(att2_16 + (size_t)(m0 + r) * 256 + s);
    }
    stageWs(op_wb, 256, 0);
    int cur = 0;

    f32x4 resid[2];

    // ---- oproj2 + LN1 ----
    {
        f32x4 acc[2] = {{0.f,0.f,0.f,0.f},{0.f,0.f,0.f,0.f}};
        for (int k = 0; k < 4; ++k) {
            if (k < 3) stageWs(op_wb + (k + 1) * 64, 256, cur ^ 1);
            else       stageWs(l1_wb, 256, cur ^ 1);
            WAIT_VM_BAR(4);
            mfma2(hc, k * 64, cur, acc);
            __builtin_amdgcn_s_barrier();
            cur ^= 1;
        }
        float s[4] = {0.f,0.f,0.f,0.f}, s2v[4] = {0.f,0.f,0.f,0.f};
#pragma unroll
        for (int cb = 0; cb < 2; ++cb) {
            int col = wv * 32 + cb * 16 + L;
            float bv = op_b[col];
#pragma unroll
            for (int i = 0; i < 4; ++i) {
                float xv = acc[cb][i] + bv + tgt_a[(size_t)(m0 + rloc + i) * 256 + col];
                acc[cb][i] = xv;
                s[i] += xv; s2v[i] += xv * xv;
            }
        }
#pragma unroll
        for (int off = 1; off < 16; off <<= 1)
#pragma unroll
            for (int i = 0; i < 4; ++i) {
                s[i]   += __shfl_xor(s[i],   off, 64);
                s2v[i] += __shfl_xor(s2v[i], off, 64);
            }
        if (L == 0)
#pragma unroll
            for (int i = 0; i < 4; ++i) { sS[wv][rloc + i] = s[i]; s2S[wv][rloc + i] = s2v[i]; }
        LK_BAR();
        float mean[4], rstd[4];
#pragma unroll
        for (int i = 0; i < 4; ++i) {
            float St = 0.f, S2t = 0.f;
#pragma unroll
            for (int w = 0; w < 8; ++w) { St += sS[w][rloc + i]; S2t += s2S[w][rloc + i]; }
            mean[i] = St * (1.f / 256.f);
            float var = S2t * (1.f / 256.f) - mean[i] * mean[i];
            rstd[i] = rsqrtf(var + 1e-5f);
        }
#pragma unroll
        for (int cb = 0; cb < 2; ++cb) {
            int col = wv * 32 + cb * 16 + L;
            float gv = ln1g[col], bt = ln1b[col];
#pragma unroll
            for (int i = 0; i < 4; ++i) {
                float y = (acc[cb][i] - mean[i]) * rstd[i] * gv + bt;
                resid[cb][i] = y;
                A1[(rloc + i) * 264 + col] = (ushort_t)f2bf1(y);
            }
        }
        // A1 visibility via next loop's WAIT_VM_BAR (lgkmcnt 0)
    }

    // ---- FFN1 chunked into FFN2 ----
    f32x4 accf[2] = {{0.f,0.f,0.f,0.f},{0.f,0.f,0.f,0.f}};
    for (int c = 0; c < 4; ++c) {
        f32x4 acch[2] = {{0.f,0.f,0.f,0.f},{0.f,0.f,0.f,0.f}};
        for (int k = 0; k < 4; ++k) {
            if (k < 3) stageWs(l1_wb + (size_t)(c * 256) * 256 + (k + 1) * 64, 256, cur ^ 1);
            else       stageWs(l2_wb + c * 256, 1024, cur ^ 1);
            WAIT_VM_BAR(4);
            mfma2(A1, k * 64, cur, acch);
            __builtin_amdgcn_s_barrier();
            cur ^= 1;
        }
        // hidden chunk -> hc (relu, bf16)
#pragma unroll
        for (int cb = 0; cb < 2; ++cb) {
            int colc = wv * 32 + cb * 16 + L;
            float bv = l1b[c * 256 + colc];
#pragma unroll
            for (int i = 0; i < 4; ++i)
                hc[(rloc + i) * 264 + colc] = (ushort_t)f2bf1(fmaxf(acch[cb][i] + bv, 0.f));
        }
        LK_BAR();
        for (int k = 0; k < 4; ++k) {
            if (k < 3)      { stageWs(l2_wb + c * 256 + (k + 1) * 64, 1024, cur ^ 1); WAIT_VM_BAR(4); }
            else if (c < 3) { stageWs(l1_wb + (size_t)((c + 1) * 256) * 256, 256, cur ^ 1); WAIT_VM_BAR(4); }
            else            { WAIT_VM_BAR(0); }
            mfma2(hc, k * 64, cur, accf);
            __builtin_amdgcn_s_barrier();
            cur ^= 1;
        }
    }

    // ---- LN3 -> out ----
    {
        float s[4] = {0.f,0.f,0.f,0.f}, s2v[4] = {0.f,0.f,0.f,0.f};
#pragma unroll
        for (int cb = 0; cb < 2; ++cb) {
            int col = wv * 32 + cb * 16 + L;
            float bv = l2b[col];
#pragma unroll
            for (int i = 0; i < 4; ++i) {
                float xv = accf[cb][i] + bv + resid[cb][i];
                accf[cb][i] = xv;
                s[i] += xv; s2v[i] += xv * xv;
            }
        }
#pragma unroll
        for (int off = 1; off < 16; off <<= 1)
#pragma unroll
            for (int i = 0; i < 4; ++i) {
                s[i]   += __shfl_xor(s[i],   off, 64);
                s2v[i] += __shfl_xor(s2v[i], off, 64);
            }
        if (L == 0)
#pragma unroll
            for (int i = 0; i < 4; ++i) { sS[wv][rloc + i] = s[i]; s2S[wv][rloc + i] = s2v[i]; }
        LK_BAR();
        float mean[4], rstd[4];
#pragma unroll
        for (int i = 0; i < 4; ++i) {
            float St = 0.f, S2t = 0.f;
#pragma unroll
            for (int w = 0; w < 8; ++w) { St += sS[w][rloc + i]; S2t += s2S[w][rloc + i]; }
            mean[i] = St * (1.f / 256.f);
            float var = S2t * (1.f / 256.f) - mean[i] * mean[i];
            rstd[i] = rsqrtf(var + 1e-5f);
        }
#pragma unroll
        for (int cb = 0; cb < 2; ++cb) {
            int col = wv * 32 + cb * 16 + L;
            float gv = ln3g[col], bt = ln3b[col];
#pragma unroll
            for (int i = 0; i < 4; ++i) {
                float y = (accf[cb][i] - mean[i]) * rstd[i] * gv + bt;
                out[(size_t)(m0 + rloc + i) * 256 + col] = y;
            }
        }
    }
}

// ---------------------------------------------------------------------------
extern "C" void kernel_launch(void* const* d_in, const int* in_sizes, int n_in,
                              void* d_out, int out_size, void* d_ws, size_t ws_size,
                              hipStream_t stream)
{
    const float* tgt    = (const float*)d_in[0];
    const float* qpos   = (const float*)d_in[1];
    const float* refp   = (const float*)d_in[2];
    const float* mem    = (const float*)d_in[3];
    const float* in_w   = (const float*)d_in[6];
    const float* in_b   = (const float*)d_in[7];
    const float* outp_w = (const float*)d_in[8];
    const float* outp_b = (const float*)d_in[9];
    const float* off_w  = (const float*)d_in[10];
    const float* off_b  = (const float*)d_in[11];
    const float* aw_w   = (const float*)d_in[12];
    const float* aw_b   = (const float*)d_in[13];
    const float* vp_w   = (const float*)d_in[14];
    const float* vp_b   = (const float*)d_in[15];
    const float* op_w   = (const float*)d_in[16];
    const float* op_b   = (const float*)d_in[17];
    const float* ln1g   = (const float*)d_in[18];
    const float* ln1b   = (const float*)d_in[19];
    const float* ln2g   = (const float*)d_in[20];
    const float* ln2b   = (const float*)d_in[21];
    const float* ln3g   = (const float*)d_in[22];
    const float* ln3b   = (const float*)d_in[23];
    const float* l1w    = (const float*)d_in[24];
    const float* l1b    = (const float*)d_in[25];
    const float* l2w    = (const float*)d_in[26];
    const float* l2b    = (const float*)d_in[27];
    float* out = (float*)d_out;
    float* ws  = (float*)d_ws;

    // workspace layout (float units) — identical to passing R8/R9 layout.
    ushort_t* qkv16    = (ushort_t*)ws;
    ushort_t* att16    = (ushort_t*)(ws + 691200);
    float*    tgt_a    = ws + 1843200;
    ushort_t* tgt16    = (ushort_t*)(ws + 1843200);     // dies before tgt_a written
    ushort_t* tq16     = (ushort_t*)(ws + 2310144);     // ends 2777088 < 2995200
    float*    px_g     = ws + 2995200;
    float*    py_g     = ws + 3456000;
    float*    aw_g     = ws + 3916800;
    ushort_t* att2_16  = (ushort_t*)(ws + 4377600);
    ushort_t* value16  = (ushort_t*)(ws + 5760000);
    ushort_t* wb       = (ushort_t*)(ws + 13364736);    // ends 13872640

    const ushort_t* in_wb   = wb + WB_IN;
    const ushort_t* vp_wb   = wb + WB_VP;
    const ushort_t* outp_wb = wb + WB_OUTP;
    const ushort_t* off_wb  = wb + WB_OFF;
    const ushort_t* aw_wb   = wb + WB_AW;
    const ushort_t* op_wb   = wb + WB_OP;
    const ushort_t* l1_wb   = wb + WB_L1;
    const ushort_t* l2_wb   = wb + WB_L2;

    dim3 b256(256);

    // 0. weights + qkv A-inputs -> bf16 (pre-swizzled)
    hipLaunchKernelGGL(cvt_weights, dim3(1408), b256, 0, stream,
                       in_w, vp_w, outp_w, off_w, aw_w, op_w, l1w, l2w, wb,
                       tgt, qpos, tgt16, tq16);
    // 1. qkv + value projection (dbuf + counted vmcnt)
    hipLaunchKernelGGL(proj_fused, dim3(1388), b256, 0, stream,
                       tq16, tgt16, in_wb, in_b, mem, vp_wb, vp_b, qkv16, value16);
    // 2. flash self-attention
    hipLaunchKernelGGL(sa_flash16, dim3(15, 32), b256, 0, stream, qkv16, att16);
    // 3. oproj + LN2 + off/aw GEMMs + softmax + coords (dbuf + counted vmcnt)
    hipLaunchKernelGGL(fused_ca, dim3(225), dim3(512), 0, stream,
                       att16, tgt, qpos, outp_wb, outp_b, ln2g, ln2b,
                       off_wb, off_b, aw_wb, aw_b, refp,
                       tgt_a, px_g, py_g, aw_g);
    // 4. deformable sampling (vectorized 4x)
    hipLaunchKernelGGL(msdeform4, dim3(900), b256, 0, stream,
                       px_g, py_g, aw_g, value16, att2_16);
    // 5. oproj2 + LN1 + FFN1 + FFN2 + LN3 (dbuf + counted vmcnt)
    hipLaunchKernelGGL(ffn_fused, dim3(225), dim3(512), 0, stream,
                       att2_16, tgt_a, op_wb, op_b, ln1g, ln1b,
                       l1_wb, l1b, l2_wb, l2b, ln3g, ln3b, out);
}